// Round 6
// baseline (206.669 us; speedup 1.0000x reference)
//
#include <hip/hip_runtime.h>
#include <hip/hip_bf16.h>

#define B_ 4
#define N_ 4096
#define D_ 128
#define KSEG 4
#define QSEG 4
#define NSEG (N_ / KSEG)   // 1024 keys per attn block
#define QSEGN (N_ / QSEG)  // 1024 q's per stats block

typedef __bf16 bf16x8 __attribute__((ext_vector_type(8)));
typedef __bf16 bf16x4 __attribute__((ext_vector_type(4)));
typedef float f32x4 __attribute__((ext_vector_type(4)));

// alpha = log2(e) / sqrt(128), folded into Qb at conversion time
#define ALPHA 0.12752361680972262f

// ws layout:
//   Qb   : bf16 [B][N][D]        @ 0       (alpha-prescaled)
//   Kb   : bf16 [B][N][D]        @ 4 MiB
//   Vt   : bf16 [B][D][N]        @ 8 MiB   (transposed V; linv-scaled in place)
//   l    : f32  [B][N]           @ 12 MiB
//   linv : f32  [B][N]           @ 12 MiB + 64 KiB
//   part : f32  [KSEG][B][N][D]  @ 13 MiB  (32 MiB)
#define OFF_KB   (4u << 20)
#define OFF_VT   (8u << 20)
#define OFF_L    (12u << 20)
#define OFF_LINV ((12u << 20) + (64u << 10))
#define OFF_PART (13u << 20)

// ---------------------------------------------------------------------------
// Kernel A: convert Q*alpha,K -> bf16; convert+transpose V -> Vt
// ---------------------------------------------------------------------------
__global__ __launch_bounds__(256) void cvt_kernel(
    const float* __restrict__ q, const float* __restrict__ k,
    const float* __restrict__ v,
    __bf16* __restrict__ qb, __bf16* __restrict__ kb, __bf16* __restrict__ vt)
{
    int bid = blockIdx.x;
    int tid = threadIdx.x;
    if (bid < 4096) {
        int i4 = bid * 256 + tid;
        const float4* src;
        __bf16* dst;
        int off;
        float sc;
        if (i4 < (B_ * N_ * D_ / 4)) { src = (const float4*)q; dst = qb; off = i4; sc = ALPHA; }
        else { src = (const float4*)k; dst = kb; off = i4 - B_ * N_ * D_ / 4; sc = 1.f; }
        float4 x = src[off];
        bf16x4 y;
        y[0] = (__bf16)(x.x * sc); y[1] = (__bf16)(x.y * sc);
        y[2] = (__bf16)(x.z * sc); y[3] = (__bf16)(x.w * sc);
        *(bf16x4*)(dst + (size_t)off * 4) = y;
    } else {
        int g = (bid - 4096) * 256 + tid;
        int kg = g & 1023;
        int rest = g >> 10;
        int d = rest & 127;
        int b = rest >> 7;
        const float* vp = v + ((size_t)b * N_ + (size_t)kg * 4) * D_ + d;
        bf16x4 y;
        y[0] = (__bf16)vp[0];
        y[1] = (__bf16)vp[D_];
        y[2] = (__bf16)vp[2 * D_];
        y[3] = (__bf16)vp[3 * D_];
        *(bf16x4*)(vt + ((size_t)b * D_ + d) * N_ + (size_t)kg * 4) = y;
    }
}

// ---------------------------------------------------------------------------
// Kernel B: column stats, 128-thread blocks (2 waves). Block = 32 keys x
// 1024 q (QSEG q-split). Wave w owns 16 keys. Q staged in 32-q tiles,
// double-buffered (stride 136), reg prefetch, one barrier/iter.
// grid = B * (N/32) * QSEG = 2048 blocks -> 8 blocks/CU, 16 waves/CU from
// 8 independent barrier domains.
// ---------------------------------------------------------------------------
__global__ __launch_bounds__(128, 4) void stats_kernel(
    const __bf16* __restrict__ qb, const __bf16* __restrict__ kb,
    float* __restrict__ l)
{
    __shared__ __bf16 qlds[2][32 * 136];   // 2 x 8.5 KiB

    int idx = blockIdx.x;
    int qseg = idx & (QSEG - 1);
    int key_base = ((idx >> 2) & 127) * 32;
    int b = idx >> 9;
    int w = threadIdx.x >> 6;              // 0..1
    int L = threadIdx.x & 63;
    int quad = L >> 4, l15 = L & 15;
    int r4 = L >> 4, c16 = L & 15;         // staging lane layout: 4 rows x 16 chunks

    const bf16x8* kv = (const bf16x8*)(kb + (size_t)b * N_ * D_);
    const bf16x8* qv = (const bf16x8*)(qb + (size_t)b * N_ * D_);

    // A-frags for this wave's 16 keys
    bf16x8 af[4];
#pragma unroll
    for (int f = 0; f < 4; ++f)
        af[f] = kv[(key_base + w * 16 + l15) * 16 + f * 4 + quad];

    int q0 = qseg * QSEGN;
    // wave w stages rows [w*16, w*16+16) of each 32-q tile
    bf16x8 qr[4];
#pragma unroll
    for (int j = 0; j < 4; ++j)
        qr[j] = qv[(q0 + w * 16 + j * 4 + r4) * 16 + c16];

    float ps[4] = {0.f, 0.f, 0.f, 0.f};   // partials for keys quad*4 + r

    const int T = QSEGN / 32;              // 32
    for (int t = 0; t < T; ++t) {
        int buf = t & 1;
#pragma unroll
        for (int j = 0; j < 4; ++j)
            *(bf16x8*)&qlds[buf][(w * 16 + j * 4 + r4) * 136 + c16 * 8] = qr[j];
        int tn = (t + 1 < T) ? t + 1 : t;
#pragma unroll
        for (int j = 0; j < 4; ++j)
            qr[j] = qv[(q0 + tn * 32 + w * 16 + j * 4 + r4) * 16 + c16];
        __syncthreads();
#pragma unroll
        for (int s = 0; s < 2; ++s) {
            bf16x8 bqf[4];
#pragma unroll
            for (int f = 0; f < 4; ++f)
                bqf[f] = *(const bf16x8*)&qlds[buf][(s * 16 + l15) * 136 + (f * 4 + quad) * 8];
            f32x4 acc = {0.f, 0.f, 0.f, 0.f};
#pragma unroll
            for (int f = 0; f < 4; ++f)
                acc = __builtin_amdgcn_mfma_f32_16x16x32_bf16(af[f], bqf[f], acc, 0, 0, 0);
#pragma unroll
            for (int r = 0; r < 4; ++r)
                ps[r] += __builtin_amdgcn_exp2f(acc[r]);
        }
    }
    // reduce over the 16 q-columns (lanes sharing a quad)
#pragma unroll
    for (int m = 1; m <= 8; m <<= 1)
#pragma unroll
        for (int r = 0; r < 4; ++r)
            ps[r] += __shfl_xor(ps[r], m, 64);
    if (l15 == 0) {
        float* dst = l + (size_t)b * N_ + key_base + w * 16 + quad * 4;
#pragma unroll
        for (int r = 0; r < 4; ++r)
            atomicAdd(dst + r, ps[r]);
    }
}

// ---------------------------------------------------------------------------
// Kernel C: linv = 1/l
// ---------------------------------------------------------------------------
__global__ __launch_bounds__(256) void recip_kernel(
    const float* __restrict__ l, float* __restrict__ linv)
{
    int i = blockIdx.x * 256 + threadIdx.x;
    linv[i] = 1.f / l[i];
}

// ---------------------------------------------------------------------------
// Kernel C2: Vt[b][d][k] *= linv[b][k]
// ---------------------------------------------------------------------------
__global__ __launch_bounds__(256) void scalev_kernel(
    const float* __restrict__ linv, __bf16* __restrict__ vt)
{
    int i = blockIdx.x * 256 + threadIdx.x;  // bf16x8 chunk index
    int row = i >> 9;                        // (b,d) row; N_/8 = 512 chunks/row
    int b = row >> 7;
    int k0 = (i & 511) * 8;
    const float* lp = linv + (size_t)b * N_ + k0;
    float4 a = *(const float4*)lp;
    float4 c = *(const float4*)(lp + 4);
    bf16x8 v = ((const bf16x8*)vt)[i];
    bf16x8 o;
    o[0] = (__bf16)((float)v[0] * a.x); o[1] = (__bf16)((float)v[1] * a.y);
    o[2] = (__bf16)((float)v[2] * a.z); o[3] = (__bf16)((float)v[3] * a.w);
    o[4] = (__bf16)((float)v[4] * c.x); o[5] = (__bf16)((float)v[5] * c.y);
    o[6] = (__bf16)((float)v[6] * c.z); o[7] = (__bf16)((float)v[7] * c.w);
    ((bf16x8*)vt)[i] = o;
}

// ---------------------------------------------------------------------------
// Kernel D: key-split attention, 128-thread blocks (2 waves). Block = 32 q x
// 1024 keys, key-tiles of 32. Phase 1: wave w computes keys [kt+16w,+16) x
// 32 q -> P in plds (stride 40). Phase 2: wave w owns d-half [64w,+64):
// ap 2 b128 + bv 4 b128 per iter. V tile (128d x 32k, stride 40) reg-staged
// with prefetch; K frags reloaded after last phase-1 use (latency covered by
// phase 2). grid = B * (N/32) * KSEG = 2048 blocks -> 8 blocks/CU.
// ---------------------------------------------------------------------------
__global__ __launch_bounds__(128, 4) void attn_kernel(
    const __bf16* __restrict__ qb, const __bf16* __restrict__ kb,
    const __bf16* __restrict__ vt, float* __restrict__ part)
{
    __shared__ __bf16 plds[32 * 40];     // 2.5 KiB
    __shared__ __bf16 vlds[128 * 40];    // 10 KiB

    int idx = blockIdx.x;
    int seg = idx & (KSEG - 1);
    int q_base = ((idx >> 2) & 127) * 32;
    int b = idx >> 9;
    int w = threadIdx.x >> 6;            // 0..1
    int L = threadIdx.x & 63;
    int quad = L >> 4, l15 = L & 15;
    int r16 = L >> 2, c4 = L & 3;        // V staging: 16 rows x 4 chunks per instr

    const bf16x8* qv = (const bf16x8*)(qb + (size_t)b * N_ * D_);
    const bf16x8* kv = (const bf16x8*)(kb + (size_t)b * N_ * D_);
    const bf16x8* vv = (const bf16x8*)(vt + (size_t)b * D_ * N_);

    // Q^T B-frags for the block's 32 q
    bf16x8 bq[2][4];
#pragma unroll
    for (int s = 0; s < 2; ++s)
#pragma unroll
        for (int f = 0; f < 4; ++f)
            bq[s][f] = qv[(q_base + s * 16 + l15) * 16 + f * 4 + quad];

    f32x4 oacc[2][4];
#pragma unroll
    for (int s2 = 0; s2 < 2; ++s2)
#pragma unroll
        for (int d2 = 0; d2 < 4; ++d2) oacc[s2][d2] = (f32x4){0.f, 0.f, 0.f, 0.f};

    int k0 = seg * NSEG;
    const int T = NSEG / 32;             // 32

    bf16x8 ak[4], vtr[4];
#pragma unroll
    for (int f = 0; f < 4; ++f)
        ak[f] = kv[(k0 + w * 16 + l15) * 16 + f * 4 + quad];
#pragma unroll
    for (int j = 0; j < 4; ++j)
        vtr[j] = vv[(size_t)(w * 64 + j * 16 + r16) * (N_ / 8) + k0 / 8 + c4];

    for (int t = 0; t < T; ++t) {
        int kt = k0 + t * 32;
        // commit current V tile to LDS (rows w*64 + j*16 + r16, cols c4*8..+8)
#pragma unroll
        for (int j = 0; j < 4; ++j)
            *(bf16x8*)&vlds[(w * 64 + j * 16 + r16) * 40 + c4 * 8] = vtr[j];
        // prefetch next V tile
        int ktn = (t + 1 < T) ? kt + 32 : kt;
#pragma unroll
        for (int j = 0; j < 4; ++j)
            vtr[j] = vv[(size_t)(w * 64 + j * 16 + r16) * (N_ / 8) + ktn / 8 + c4];

        // phase 1: E tile (this wave: keys [kt+16w,+16) x 32 q)
#pragma unroll
        for (int s = 0; s < 2; ++s) {
            f32x4 acc = {0.f, 0.f, 0.f, 0.f};
#pragma unroll
            for (int f = 0; f < 4; ++f)
                acc = __builtin_amdgcn_mfma_f32_16x16x32_bf16(ak[f], bq[s][f], acc, 0, 0, 0);
            bf16x4 p;
            p[0] = (__bf16)__builtin_amdgcn_exp2f(acc[0]);
            p[1] = (__bf16)__builtin_amdgcn_exp2f(acc[1]);
            p[2] = (__bf16)__builtin_amdgcn_exp2f(acc[2]);
            p[3] = (__bf16)__builtin_amdgcn_exp2f(acc[3]);
            *(bf16x4*)&plds[(s * 16 + l15) * 40 + w * 16 + quad * 4] = p;
        }
        // reload K frags for next tile (last use was above; phase 2 covers latency)
#pragma unroll
        for (int f = 0; f < 4; ++f)
            ak[f] = kv[(ktn + w * 16 + l15) * 16 + f * 4 + quad];
        __syncthreads();   // plds + vlds writes visible

        // phase 2: O += P * Vt (this wave: 32 q x d [64w, +64), 32 k)
        bf16x8 ap[2];
#pragma unroll
        for (int s2 = 0; s2 < 2; ++s2)
            ap[s2] = *(const bf16x8*)&plds[(s2 * 16 + l15) * 40 + quad * 8];
#pragma unroll
        for (int d2 = 0; d2 < 4; ++d2) {
            bf16x8 bv = *(const bf16x8*)&vlds[(w * 64 + d2 * 16 + l15) * 40 + quad * 8];
#pragma unroll
            for (int s2 = 0; s2 < 2; ++s2)
                oacc[s2][d2] = __builtin_amdgcn_mfma_f32_16x16x32_bf16(
                    ap[s2], bv, oacc[s2][d2], 0, 0, 0);
        }
        __syncthreads();   // protect plds/vlds for next iteration
    }

    // epilogue: q = q_base + s2*16 + quad*4 + r ; d = w*64 + d2*16 + l15
    float* op = part + ((size_t)seg * B_ * N_ + (size_t)b * N_ + q_base) * D_ + w * 64;
#pragma unroll
    for (int s2 = 0; s2 < 2; ++s2)
#pragma unroll
        for (int d2 = 0; d2 < 4; ++d2)
#pragma unroll
            for (int r = 0; r < 4; ++r)
                op[(s2 * 16 + quad * 4 + r) * D_ + d2 * 16 + l15] = oacc[s2][d2][r];
}

// ---------------------------------------------------------------------------
// Kernel E: out = sum of KSEG partials
// ---------------------------------------------------------------------------
__global__ __launch_bounds__(256) void reduce_kernel(
    const float* __restrict__ part, float* __restrict__ out)
{
    int i = blockIdx.x * 256 + threadIdx.x;
    const f32x4* p = (const f32x4*)part;
    f32x4 s = p[i];
#pragma unroll
    for (int sgi = 1; sgi < KSEG; ++sgi) {
        f32x4 t = p[(size_t)sgi * (B_ * N_ * D_ / 4) + i];
        s[0] += t[0]; s[1] += t[1]; s[2] += t[2]; s[3] += t[3];
    }
    ((f32x4*)out)[i] = s;
}

extern "C" void kernel_launch(void* const* d_in, const int* in_sizes, int n_in,
                              void* d_out, int out_size, void* d_ws, size_t ws_size,
                              hipStream_t stream) {
    const float* q = (const float*)d_in[0];
    const float* k = (const float*)d_in[1];
    const float* v = (const float*)d_in[2];
    float* out = (float*)d_out;
    char* ws = (char*)d_ws;
    __bf16* qb = (__bf16*)(ws);
    __bf16* kb = (__bf16*)(ws + OFF_KB);
    __bf16* vt = (__bf16*)(ws + OFF_VT);
    float* l    = (float*)(ws + OFF_L);
    float* linv = (float*)(ws + OFF_LINV);
    float* part = (float*)(ws + OFF_PART);

    hipLaunchKernelGGL(cvt_kernel, dim3(6144), dim3(256), 0, stream, q, k, v, qb, kb, vt);
    hipMemsetAsync(l, 0, (size_t)B_ * N_ * sizeof(float), stream);
    hipLaunchKernelGGL(stats_kernel, dim3(B_ * (N_ / 32) * QSEG), dim3(128), 0, stream, qb, kb, l);
    hipLaunchKernelGGL(recip_kernel, dim3(B_ * N_ / 256), dim3(256), 0, stream, l, linv);
    hipLaunchKernelGGL(scalev_kernel, dim3(B_ * D_ * N_ / 8 / 256), dim3(256), 0, stream, linv, vt);
    hipLaunchKernelGGL(attn_kernel, dim3(B_ * (N_ / 32) * KSEG), dim3(128), 0, stream, qb, kb, vt, part);
    hipLaunchKernelGGL(reduce_kernel, dim3(B_ * N_ * D_ / 4 / 256), dim3(256), 0, stream, part, out);
}